// Round 1
// baseline (14508.702 us; speedup 1.0000x reference)
//
#include <hip/hip_runtime.h>

// LangModelWithLSTM on MI355X (gfx950). fp32 inputs, fp32 output.
// embed-concat -> [xg GEMM -> persistent biLSTM recurrence] x2 -> MLP head.
// fp32 accuracy via bf16 MFMA with hi/lo splitting:
//   GEMMs: K-tripled streams  A={a_hi,a_lo,a_hi} x B={w_hi,w_hi,w_lo}
//   recurrence: (h_hi + h_lo) x W_hi   (W_lo term negligible)
// Cross-WG h exchange v2: h published as separate contiguous hi/lo bf16 planes
// (AGENT-scope atomics through MALL); consumers load MFMA A-fragments DIRECTLY
// from MALL (no LDS staging, no de-interleave). Per-WAVE flags: a wave's lane0
// RELEASE store drains that wave's vmcnt, so no pre-flag barrier. Yt stores
// issued after the flag so their HBM drain overlaps the next poll. One
// __syncthreads per step (gate exchange, double-buffered).
// B=16, S=512, H=512, D_IN=1024, 4H=2048, HID=1024, C=5, L=2 bidirectional.

typedef unsigned short u16;
typedef unsigned int   u32;
typedef unsigned long long u64;
typedef short s16x8 __attribute__((ext_vector_type(8)));   // MFMA A/B frag (8 bf16)
typedef float f32x4 __attribute__((ext_vector_type(4)));   // MFMA accumulator

__device__ __forceinline__ float b2f(u16 h) { return __uint_as_float(((u32)h) << 16); }
__device__ __forceinline__ u16 f2b(float x) {            // round-to-nearest-even
  u32 u = __float_as_uint(x);
  return (u16)((u + 0x7fffu + ((u >> 16) & 1u)) >> 16);
}
// A-side pair -> 3 u32 words: u16 stream {h0,l0,h0, h1,l1,h1}
__device__ __forceinline__ void packA3(float v0, float v1, u32& w0, u32& w1, u32& w2) {
  u16 h0 = f2b(v0), h1 = f2b(v1);
  u16 l0 = f2b(v0 - b2f(h0)), l1 = f2b(v1 - b2f(h1));
  w0 = (u32)h0 | ((u32)l0 << 16);
  w1 = (u32)h0 | ((u32)h1 << 16);
  w2 = (u32)l1 | ((u32)h1 << 16);
}
// B-side pair -> 3 u32 words: u16 stream {h0,h0,l0, h1,h1,l1}
__device__ __forceinline__ void packB3(float v0, float v1, u32& w0, u32& w1, u32& w2) {
  u16 h0 = f2b(v0), h1 = f2b(v1);
  u16 l0 = f2b(v0 - b2f(h0)), l1 = f2b(v1 - b2f(h1));
  w0 = (u32)h0 | ((u32)h0 << 16);
  w1 = (u32)l0 | ((u32)h1 << 16);
  w2 = (u32)h1 | ((u32)l1 << 16);
}

// ---------------------------------------------------------------- embed -> A3 triple
__global__ __launch_bounds__(256) void k_embed(const int* __restrict__ x,
    const float* __restrict__ lang, const float* __restrict__ emb, u16* __restrict__ A3) {
  const int m = blockIdx.x;                  // 8192 rows = b*512+s
  const int k = threadIdx.x * 4;             // 4 source elems
  const float* src = (k < 768) ? (lang + (size_t)m * 768 + k)
                               : (emb + (size_t)x[m] * 256 + (k - 768));
  float4 v = *(const float4*)src;
  u32 w0, w1, w2, w3, w4, w5;
  packA3(v.x, v.y, w0, w1, w2);
  packA3(v.z, v.w, w3, w4, w5);
  uint2* dst = (uint2*)(A3 + (size_t)m * 3072 + 3 * k);
  dst[0] = make_uint2(w0, w1); dst[1] = make_uint2(w2, w3); dst[2] = make_uint2(w4, w5);
}

// ---------------------------------------------------------------- weight preps
// fp32 W [rows][1024] -> triple [rows][3072]; one quad per thread.
__global__ __launch_bounds__(256) void k_prepw(const float* __restrict__ W,
    u16* __restrict__ W3, int nq) {
  const int idx = blockIdx.x * 256 + threadIdx.x;
  if (idx >= nq) return;
  const int base = idx * 4, row = base >> 10, k = base & 1023;
  float4 v = *(const float4*)(W + base);
  u32 w0, w1, w2, w3, w4, w5;
  packB3(v.x, v.y, w0, w1, w2);
  packB3(v.z, v.w, w3, w4, w5);
  uint2* dst = (uint2*)(W3 + (size_t)row * 3072 + 3 * k);
  dst[0] = make_uint2(w0, w1); dst[1] = make_uint2(w2, w3); dst[2] = make_uint2(w4, w5);
}
// Whh fp32 flat [4194304] -> hi bf16 plane (lo plane dropped in recurrence)
__global__ __launch_bounds__(256) void k_prepwh(const float* __restrict__ W,
    u16* __restrict__ hi) {
  const int idx = blockIdx.x * 256 + threadIdx.x;   // 1,048,576 quads
  const int base = idx * 4;
  float4 v = *(const float4*)(W + base);
  float vv[4] = {v.x, v.y, v.z, v.w};
  u16 h[4];
#pragma unroll
  for (int i = 0; i < 4; ++i) h[i] = f2b(vv[i]);
  *(uint2*)(hi + base) = make_uint2((u32)h[0] | ((u32)h[1] << 16), (u32)h[2] | ((u32)h[3] << 16));
}
__global__ __launch_bounds__(256) void k_prepb(const float* __restrict__ bih,
    const float* __restrict__ bhh, float* __restrict__ bsum) {
  const int tid = blockIdx.x * 256 + threadIdx.x;   // 8192
  bsum[tid] = bih[tid] + bhh[tid];
}
// act fp32 [8192][1024] -> A3 triple
__global__ __launch_bounds__(256) void k_tri(const float* __restrict__ act, u16* __restrict__ A3) {
  const int idx = blockIdx.x * 256 + threadIdx.x;   // 2,097,152 quads
  const int base = idx * 4, row = base >> 10, k = base & 1023;
  float4 v = *(const float4*)(act + base);
  u32 w0, w1, w2, w3, w4, w5;
  packA3(v.x, v.y, w0, w1, w2);
  packA3(v.z, v.w, w3, w4, w5);
  uint2* dst = (uint2*)(A3 + (size_t)row * 3072 + 3 * k);
  dst[0] = make_uint2(w0, w1); dst[1] = make_uint2(w2, w3); dst[2] = make_uint2(w4, w5);
}

// ---------------------------------------------------------------- GEMM (m97 style)
// C[m][n] = sum_k A[m][k]*B[n][k] + bias[n]. 128x128 tile, BK=32, 4 waves.
// EPI=0: fp32 -> xg layout [dir=n>>11][(s*16+b)][n&2047]  (N==4096)
// EPI=1: fp32 [m][N] + leaky-relu -> act.
template <int EPI>
__global__ __launch_bounds__(256) void k_gemm(const u16* __restrict__ A,
    const u16* __restrict__ B, const float* __restrict__ bias, float* __restrict__ outp,
    int Ka, int N) {
  __shared__ u16 As[4096];   // [128][32]
  __shared__ u16 Bs[4096];
  const int tid = threadIdx.x, wave = tid >> 6, lane = tid & 63;
  const int bm0 = blockIdx.x * 128, bn0 = blockIdx.y * 128;
  const int wm = (wave & 1) * 64, wn = (wave >> 1) * 64;
  const int kq = (lane >> 4) * 8;
  f32x4 acc[4][4];
#pragma unroll
  for (int i = 0; i < 4; ++i)
#pragma unroll
    for (int j = 0; j < 4; ++j) acc[i][j] = (f32x4){0.f, 0.f, 0.f, 0.f};

  const int srow = tid >> 2, soff = (tid & 3) * 8;
  const u16* Ag  = A + (size_t)(bm0 + srow) * Ka + soff;
  const u16* Ag2 = Ag + (size_t)64 * Ka;
  const u16* Bg  = B + (size_t)(bn0 + srow) * Ka + soff;
  const u16* Bg2 = Bg + (size_t)64 * Ka;
  u16* sA = As + wave * 512;
  u16* sB = Bs + wave * 512;

  for (int k0 = 0; k0 < Ka; k0 += 32) {
    __syncthreads();
    __builtin_amdgcn_global_load_lds((const __attribute__((address_space(1))) void*)(Ag + k0),
        (__attribute__((address_space(3))) void*)sA, 16, 0, 0);
    __builtin_amdgcn_global_load_lds((const __attribute__((address_space(1))) void*)(Ag2 + k0),
        (__attribute__((address_space(3))) void*)(sA + 2048), 16, 0, 0);
    __builtin_amdgcn_global_load_lds((const __attribute__((address_space(1))) void*)(Bg + k0),
        (__attribute__((address_space(3))) void*)sB, 16, 0, 0);
    __builtin_amdgcn_global_load_lds((const __attribute__((address_space(1))) void*)(Bg2 + k0),
        (__attribute__((address_space(3))) void*)(sB + 2048), 16, 0, 0);
    __syncthreads();
    s16x8 af[4], bf[4];
#pragma unroll
    for (int mi = 0; mi < 4; ++mi) af[mi] = *(const s16x8*)(As + (wm + mi * 16 + (lane & 15)) * 32 + kq);
#pragma unroll
    for (int ni = 0; ni < 4; ++ni) bf[ni] = *(const s16x8*)(Bs + (wn + ni * 16 + (lane & 15)) * 32 + kq);
#pragma unroll
    for (int mi = 0; mi < 4; ++mi)
#pragma unroll
      for (int ni = 0; ni < 4; ++ni)
        acc[mi][ni] = __builtin_amdgcn_mfma_f32_16x16x32_bf16(af[mi], bf[ni], acc[mi][ni], 0, 0, 0);
  }

#pragma unroll
  for (int mi = 0; mi < 4; ++mi)
#pragma unroll
    for (int r = 0; r < 4; ++r) {
      const int m = bm0 + wm + mi * 16 + (lane >> 4) * 4 + r;
#pragma unroll
      for (int ni = 0; ni < 4; ++ni) {
        const int n = bn0 + wn + ni * 16 + (lane & 15);
        float v = acc[mi][ni][r] + bias[n];
        if (EPI == 0) {
          const size_t off = (size_t)(n >> 11) * 16777216u
                           + (size_t)((m & 511) * 16 + (m >> 9)) * 2048 + (n & 2047);
          outp[off] = v;
        } else {
          v = (v > 0.f) ? v : 0.01f * v;
          outp[(size_t)m * N + n] = v;
        }
      }
    }
}

// ---------------------------------------------------------------- persistent biLSTM v2
// 32 WGs: dir = blk>>4; each WG owns 32 hidden units (4 gates x 16 batches).
// Wave g = gate g, 2 column-tiles of 16 units. W_hi frags pinned in VGPRs.
// h ring: [dir][slot 0..3] of {hi plane [16][512] u16, lo plane [16][512] u16}
// (32KB per slot). Producers store 2 coherent u32 per thread; a consumer lane's
// A-frag = 16 contiguous bytes of a plane -> 2 coherent u64 loads straight into
// MFMA operands. 64 flags/dir (one per wave): lane0 RELEASE store drains the
// wave's vmcnt, no barrier. Poll = one flag per lane + ballot. Yt stores after
// the flag so their HBM drain overlaps the next poll. One __syncthreads/step.
__global__ __launch_bounds__(256, 1) void k_rec(const float* __restrict__ xg,
    const u16* __restrict__ WhiP, const int* __restrict__ lens, u16* __restrict__ Yt,
    u16* __restrict__ hbuf, u32* __restrict__ flags, int flagbase) {
  __shared__ float gx[2][4][16][33];   // [parity][gate][batch][32 units + pad]
  const int tid = threadIdx.x, wave = tid >> 6, lane = tid & 63;
  const int dir = blockIdx.x >> 4, slice = blockIdx.x & 15, ubase = slice * 32;
  const int kq = (lane >> 4) * 8;
  const int col = lane & 15;
  const int bq = (lane >> 4) * 4;

  s16x8 bfrag[2][16];                  // W_hi rows g = wave*512 + ubase + j*16 + col
#pragma unroll
  for (int j = 0; j < 2; ++j) {
    const u16* wr = WhiP + ((size_t)dir * 2048 + wave * 512 + ubase + j * 16 + col) * 512 + kq;
#pragma unroll
    for (int kt = 0; kt < 16; ++kt) bfrag[j][kt] = *(const s16x8*)(wr + kt * 32);
  }
  const int pp = tid & 15, bb = tid >> 4;   // pointwise: units 2pp,2pp+1, batch bb
  const int len_b = lens[bb];
  float c0 = 0.f, h0v = 0.f, c1 = 0.f, h1v = 0.f;
  const float* xgp = xg + (size_t)dir * 16777216u;
  u32* myflags = flags + dir * 64;
  u16* hbase = hbuf + (size_t)dir * 65536;       // 4 slots x 16384 u16

  for (int s = 0; s < 512; ++s) {
    const int t = dir ? (511 - s) : s;
    // prefetch this step's xg (in flight during poll); acc rows b=bq+r, cols j*16+col
    const float* xr = xgp + ((size_t)t * 16 + bq) * 2048 + wave * 512 + ubase + col;
    f32x4 a0, a1;
    a0[0] = xr[0];  a0[1] = xr[2048]; a0[2] = xr[4096]; a0[3] = xr[6144];
    a1[0] = xr[16]; a1[1] = xr[2064]; a1[2] = xr[4112]; a1[3] = xr[6160];

    if (s > 0) {
      const u32 tgt = (u32)(flagbase + s);
      bool ok;
      do {                                             // one flag per lane
        u32 f = __hip_atomic_load(&myflags[lane], __ATOMIC_RELAXED, __HIP_MEMORY_SCOPE_AGENT);
        ok = (~__ballot(f >= tgt)) == 0ull;
        if (!ok) __builtin_amdgcn_s_sleep(1);
      } while (!ok);
      // direct MALL -> A-frag loads; MFMAs pipeline against in-flight loads
      const u16* hp = hbase + (size_t)(s & 3) * 16384 + col * 512 + kq;   // hi plane
      const u16* lp = hp + 8192;                                          // lo plane
      f32x4 l0 = (f32x4){0.f, 0.f, 0.f, 0.f}, l1 = (f32x4){0.f, 0.f, 0.f, 0.f};
#pragma unroll
      for (int kt = 0; kt < 16; ++kt) {
        union { u64 q[2]; s16x8 v; } ah, al;
        const u64* ph = (const u64*)(hp + kt * 32);
        const u64* pl = (const u64*)(lp + kt * 32);
        ah.q[0] = __hip_atomic_load(ph,     __ATOMIC_RELAXED, __HIP_MEMORY_SCOPE_AGENT);
        ah.q[1] = __hip_atomic_load(ph + 1, __ATOMIC_RELAXED, __HIP_MEMORY_SCOPE_AGENT);
        al.q[0] = __hip_atomic_load(pl,     __ATOMIC_RELAXED, __HIP_MEMORY_SCOPE_AGENT);
        al.q[1] = __hip_atomic_load(pl + 1, __ATOMIC_RELAXED, __HIP_MEMORY_SCOPE_AGENT);
        a0 = __builtin_amdgcn_mfma_f32_16x16x32_bf16(ah.v, bfrag[0][kt], a0, 0, 0, 0);
        a1 = __builtin_amdgcn_mfma_f32_16x16x32_bf16(ah.v, bfrag[1][kt], a1, 0, 0, 0);
        l0 = __builtin_amdgcn_mfma_f32_16x16x32_bf16(al.v, bfrag[0][kt], l0, 0, 0, 0);
        l1 = __builtin_amdgcn_mfma_f32_16x16x32_bf16(al.v, bfrag[1][kt], l1, 0, 0, 0);
      }
      a0 += l0; a1 += l1;
    }
    float (*g)[16][33] = gx[s & 1];
#pragma unroll
    for (int r = 0; r < 4; ++r) {
      g[wave][bq + r][col] = a0[r];
      g[wave][bq + r][16 + col] = a1[r];
    }
    __syncthreads();                     // gate write -> read (double-buffered)

    const int u0 = 2 * pp, u1 = u0 + 1;
    const float gi0 = g[0][bb][u0], gf0 = g[1][bb][u0], gg0 = g[2][bb][u0], go0 = g[3][bb][u0];
    const float gi1 = g[0][bb][u1], gf1 = g[1][bb][u1], gg1 = g[2][bb][u1], go1 = g[3][bb][u1];
    const float ii0 = 1.f / (1.f + __expf(-gi0)),  ii1 = 1.f / (1.f + __expf(-gi1));
    const float ff0 = 1.f / (1.f + __expf(-gf0)),  ff1 = 1.f / (1.f + __expf(-gf1));
    const float gz0 = 1.f - 2.f / (__expf(2.f * gg0) + 1.f);   // tanh
    const float gz1 = 1.f - 2.f / (__expf(2.f * gg1) + 1.f);
    const float oo0 = 1.f / (1.f + __expf(-go0)),  oo1 = 1.f / (1.f + __expf(-go1));
    const float cn0 = ff0 * c0 + ii0 * gz0,        cn1 = ff1 * c1 + ii1 * gz1;
    const float hn0 = oo0 * (1.f - 2.f / (__expf(2.f * cn0) + 1.f));
    const float hn1 = oo1 * (1.f - 2.f / (__expf(2.f * cn1) + 1.f));
    const bool mk = (t < len_b);
    c0 = mk ? cn0 : c0;  h0v = mk ? hn0 : h0v;
    c1 = mk ? cn1 : c1;  h1v = mk ? hn1 : h1v;

    if (s < 511) {                       // publish carried h to ring slot (s+1)&3
      const u16 s0h = f2b(h0v), s0l = f2b(h0v - b2f(s0h));
      const u16 s1h = f2b(h1v), s1l = f2b(h1v - b2f(s1h));
      u16* slot = hbase + (size_t)((s + 1) & 3) * 16384;
      u32* dh = (u32*)(slot + (size_t)bb * 512 + ubase) + pp;          // hi plane
      u32* dl = (u32*)(slot + 8192 + (size_t)bb * 512 + ubase) + pp;   // lo plane
      __hip_atomic_store(dh, (u32)s0h | ((u32)s1h << 16), __ATOMIC_RELAXED, __HIP_MEMORY_SCOPE_AGENT);
      __hip_atomic_store(dl, (u32)s0l | ((u32)s1l << 16), __ATOMIC_RELAXED, __HIP_MEMORY_SCOPE_AGENT);
      if (lane == 0)                     // wave-level release: drains wave vmcnt
        __hip_atomic_store(&myflags[slice * 4 + wave], (u32)(flagbase + s + 1),
                           __ATOMIC_RELEASE, __HIP_MEMORY_SCOPE_AGENT);
    }
    __builtin_amdgcn_sched_barrier(0);   // keep Yt stores after the flag

    // output: next-layer A-triple {hi,lo,hi} of y = h_new*mask (unit pair -> 12B)
    const float y0 = mk ? hn0 : 0.f, y1 = mk ? hn1 : 0.f;
    u32 w0, w1, w2;
    packA3(y0, y1, w0, w1, w2);
    const int ug = dir * 512 + ubase + u0;               // even
    u32* yp = (u32*)(Yt + (size_t)(bb * 512 + t) * 3072 + 3 * ug);
    yp[0] = w0; yp[1] = w1; yp[2] = w2;
  }
}

// ---------------------------------------------------------------- head: out = a2 @ W3^T + b3
__global__ __launch_bounds__(256) void k_head(const float* __restrict__ a2,
    const float* __restrict__ W3, const float* __restrict__ b3, float* __restrict__ out) {
  const int m = (blockIdx.x * 256 + threadIdx.x) >> 6;   // wave per row
  const int lane = threadIdx.x & 63;
  const float* row = a2 + (size_t)m * 1024;
  float s[5] = {0.f, 0.f, 0.f, 0.f, 0.f};
  for (int j = lane; j < 1024; j += 64) {
    const float v = row[j];
#pragma unroll
    for (int c = 0; c < 5; ++c) s[c] += v * W3[c * 1024 + j];
  }
#pragma unroll
  for (int c = 0; c < 5; ++c)
    for (int off = 32; off > 0; off >>= 1) s[c] += __shfl_down(s[c], off, 64);
  if (lane == 0)
#pragma unroll
    for (int c = 0; c < 5; ++c) out[(size_t)m * 5 + c] = s[c] + b3[c];   // fp32 output
}

// ---------------------------------------------------------------- launch
extern "C" void kernel_launch(void* const* d_in, const int* in_sizes, int n_in,
                              void* d_out, int out_size, void* d_ws, size_t ws_size,
                              hipStream_t stream) {
  const int*   x    = (const int*)d_in[0];
  const int*   lens = (const int*)d_in[1];
  const float* lang = (const float*)d_in[2];
  const float* emb  = (const float*)d_in[3];
  const float* Wih  = (const float*)d_in[4];   // [2][2][2048][1024]
  const float* Whh  = (const float*)d_in[5];   // [2][2][2048][512]
  const float* bih  = (const float*)d_in[6];
  const float* bhh  = (const float*)d_in[7];
  const float* W1   = (const float*)d_in[8];
  const float* b1   = (const float*)d_in[9];
  const float* W2   = (const float*)d_in[10];
  const float* b2   = (const float*)d_in[11];
  const float* W3   = (const float*)d_in[12];
  const float* b3   = (const float*)d_in[13];
  float* out = (float*)d_out;
  char* ws = (char*)d_ws;

  // workspace (~223 MiB). act overlays xg (xg dead after k_rec layer 1).
  float* xg     = (float*)(ws + 0);             // [2][8192][2048] f32  134,217,728
  float* act    = (float*)(ws + 0);             //  [8192][1024] f32 overlay
  u16*   A3     = (u16*)(ws + 134217728);       //  [8192][3072] u16     50,331,648
  u16*   wb3    = (u16*)(ws + 184549376);       //  [4096][3072] u16     25,165,824
  u16*   whh_hi = (u16*)(ws + 209715200);       //  [2][2][2048][512]     8,388,608
  u16*   w3b    = (u16*)(ws + 226492416);       //  [1024][3072] u16      6,291,456
  u16*   hbuf   = (u16*)(ws + 232783872);       //  [2][4][32KB] ring       262,144
  float* bsum   = (float*)(ws + 233046016);     //  [2][2][2048]             32,768
  u32*   flags  = (u32*)(ws + 233078784);       //  [2][64]                    512

  hipMemsetAsync(flags, 0, 512, stream);
  k_prepb<<<32, 256, 0, stream>>>(bih, bhh, bsum);
  k_prepwh<<<4096, 256, 0, stream>>>(Whh, whh_hi);
  k_embed<<<8192, 256, 0, stream>>>(x, lang, emb, A3);

  // layer 0
  k_prepw<<<4096, 256, 0, stream>>>(Wih, wb3, 1048576);
  k_gemm<0><<<dim3(64, 32), 256, 0, stream>>>(A3, wb3, bsum, xg, 3072, 4096);
  k_rec<<<32, 256, 0, stream>>>(xg, whh_hi, lens, A3, hbuf, flags, 0);
  // layer 1
  k_prepw<<<4096, 256, 0, stream>>>(Wih + 4194304, wb3, 1048576);
  k_gemm<0><<<dim3(64, 32), 256, 0, stream>>>(A3, wb3, bsum + 4096, xg, 3072, 4096);
  k_rec<<<32, 256, 0, stream>>>(xg, whh_hi + 2097152, lens, A3, hbuf, flags, 512);
  // head
  k_prepw<<<1024, 256, 0, stream>>>(W1, w3b, 262144);
  k_gemm<1><<<dim3(64, 8), 256, 0, stream>>>(A3, w3b, b1, act, 3072, 1024);
  k_tri<<<8192, 256, 0, stream>>>(act, A3);
  k_prepw<<<1024, 256, 0, stream>>>(W2, w3b, 262144);
  k_gemm<1><<<dim3(64, 8), 256, 0, stream>>>(A3, w3b, b2, act, 3072, 1024);
  k_head<<<2048, 256, 0, stream>>>(act, W3, b3, out);
}

// Round 2
// 10857.104 us; speedup vs baseline: 1.3363x; 1.3363x over previous
//
#include <hip/hip_runtime.h>

// LangModelWithLSTM on MI355X (gfx950). fp32 inputs, fp32 output.
// embed-concat -> [xg GEMM -> persistent biLSTM recurrence] x2 -> MLP head.
// fp32 accuracy via bf16 MFMA with hi/lo splitting:
//   GEMMs: K-tripled streams  A={a_hi,a_lo,a_hi} x B={w_hi,w_hi,w_lo}
//   recurrence: (h_hi + h_lo) x W_hi   (W_lo term negligible)
// Cross-WG h exchange v3 (v1 LDS staging + v2's structural fixes):
//   - h published as separate contiguous hi/lo bf16 planes (AGENT atomics to
//     MALL); consumer staging is a pure copy: 16 atomic u64 loads -> ds_write_b64.
//   - per-WAVE flags: lane0 RELEASE store drains the wave's vmcnt -> no barrier
//     before the flag; Yt (next-layer) stores issued AFTER the flag.
//   - wave owns all 4 gates for 8 units (tile0=i/f, tile1=g/o); gate exchange
//     via __shfl_xor(8) in-wave; pointwise duplicated across lane pairs.
//   -> ONE __syncthreads per step (staging->ds_read); hs parity double-buffered.
// B=16, S=512, H=512, D_IN=1024, 4H=2048, HID=1024, C=5, L=2 bidirectional.

typedef unsigned short u16;
typedef unsigned int   u32;
typedef unsigned long long u64;
typedef short s16x8 __attribute__((ext_vector_type(8)));   // MFMA A/B frag (8 bf16)
typedef float f32x4 __attribute__((ext_vector_type(4)));   // MFMA accumulator

__device__ __forceinline__ float b2f(u16 h) { return __uint_as_float(((u32)h) << 16); }
__device__ __forceinline__ u16 f2b(float x) {            // round-to-nearest-even
  u32 u = __float_as_uint(x);
  return (u16)((u + 0x7fffu + ((u >> 16) & 1u)) >> 16);
}
// A-side pair -> 3 u32 words: u16 stream {h0,l0,h0, h1,l1,h1}
__device__ __forceinline__ void packA3(float v0, float v1, u32& w0, u32& w1, u32& w2) {
  u16 h0 = f2b(v0), h1 = f2b(v1);
  u16 l0 = f2b(v0 - b2f(h0)), l1 = f2b(v1 - b2f(h1));
  w0 = (u32)h0 | ((u32)l0 << 16);
  w1 = (u32)h0 | ((u32)h1 << 16);
  w2 = (u32)l1 | ((u32)h1 << 16);
}
// B-side pair -> 3 u32 words: u16 stream {h0,h0,l0, h1,h1,l1}
__device__ __forceinline__ void packB3(float v0, float v1, u32& w0, u32& w1, u32& w2) {
  u16 h0 = f2b(v0), h1 = f2b(v1);
  u16 l0 = f2b(v0 - b2f(h0)), l1 = f2b(v1 - b2f(h1));
  w0 = (u32)h0 | ((u32)h0 << 16);
  w1 = (u32)l0 | ((u32)h1 << 16);
  w2 = (u32)h1 | ((u32)l1 << 16);
}

// ---------------------------------------------------------------- embed -> A3 triple
__global__ __launch_bounds__(256) void k_embed(const int* __restrict__ x,
    const float* __restrict__ lang, const float* __restrict__ emb, u16* __restrict__ A3) {
  const int m = blockIdx.x;                  // 8192 rows = b*512+s
  const int k = threadIdx.x * 4;             // 4 source elems
  const float* src = (k < 768) ? (lang + (size_t)m * 768 + k)
                               : (emb + (size_t)x[m] * 256 + (k - 768));
  float4 v = *(const float4*)src;
  u32 w0, w1, w2, w3, w4, w5;
  packA3(v.x, v.y, w0, w1, w2);
  packA3(v.z, v.w, w3, w4, w5);
  uint2* dst = (uint2*)(A3 + (size_t)m * 3072 + 3 * k);
  dst[0] = make_uint2(w0, w1); dst[1] = make_uint2(w2, w3); dst[2] = make_uint2(w4, w5);
}

// ---------------------------------------------------------------- weight preps
// fp32 W [rows][1024] -> triple [rows][3072]; one quad per thread.
__global__ __launch_bounds__(256) void k_prepw(const float* __restrict__ W,
    u16* __restrict__ W3, int nq) {
  const int idx = blockIdx.x * 256 + threadIdx.x;
  if (idx >= nq) return;
  const int base = idx * 4, row = base >> 10, k = base & 1023;
  float4 v = *(const float4*)(W + base);
  u32 w0, w1, w2, w3, w4, w5;
  packB3(v.x, v.y, w0, w1, w2);
  packB3(v.z, v.w, w3, w4, w5);
  uint2* dst = (uint2*)(W3 + (size_t)row * 3072 + 3 * k);
  dst[0] = make_uint2(w0, w1); dst[1] = make_uint2(w2, w3); dst[2] = make_uint2(w4, w5);
}
// Whh fp32 flat [4194304] -> hi bf16 plane (lo plane dropped in recurrence)
__global__ __launch_bounds__(256) void k_prepwh(const float* __restrict__ W,
    u16* __restrict__ hi) {
  const int idx = blockIdx.x * 256 + threadIdx.x;   // 1,048,576 quads
  const int base = idx * 4;
  float4 v = *(const float4*)(W + base);
  float vv[4] = {v.x, v.y, v.z, v.w};
  u16 h[4];
#pragma unroll
  for (int i = 0; i < 4; ++i) h[i] = f2b(vv[i]);
  *(uint2*)(hi + base) = make_uint2((u32)h[0] | ((u32)h[1] << 16), (u32)h[2] | ((u32)h[3] << 16));
}
__global__ __launch_bounds__(256) void k_prepb(const float* __restrict__ bih,
    const float* __restrict__ bhh, float* __restrict__ bsum) {
  const int tid = blockIdx.x * 256 + threadIdx.x;   // 8192
  bsum[tid] = bih[tid] + bhh[tid];
}
// act fp32 [8192][1024] -> A3 triple
__global__ __launch_bounds__(256) void k_tri(const float* __restrict__ act, u16* __restrict__ A3) {
  const int idx = blockIdx.x * 256 + threadIdx.x;   // 2,097,152 quads
  const int base = idx * 4, row = base >> 10, k = base & 1023;
  float4 v = *(const float4*)(act + base);
  u32 w0, w1, w2, w3, w4, w5;
  packA3(v.x, v.y, w0, w1, w2);
  packA3(v.z, v.w, w3, w4, w5);
  uint2* dst = (uint2*)(A3 + (size_t)row * 3072 + 3 * k);
  dst[0] = make_uint2(w0, w1); dst[1] = make_uint2(w2, w3); dst[2] = make_uint2(w4, w5);
}

// ---------------------------------------------------------------- GEMM (m97 style)
// C[m][n] = sum_k A[m][k]*B[n][k] + bias[n]. 128x128 tile, BK=32, 4 waves.
// EPI=0: fp32 -> xg layout [dir=n>>11][(s*16+b)][n&2047]  (N==4096)
// EPI=1: fp32 [m][N] + leaky-relu -> act.
template <int EPI>
__global__ __launch_bounds__(256) void k_gemm(const u16* __restrict__ A,
    const u16* __restrict__ B, const float* __restrict__ bias, float* __restrict__ outp,
    int Ka, int N) {
  __shared__ u16 As[4096];   // [128][32]
  __shared__ u16 Bs[4096];
  const int tid = threadIdx.x, wave = tid >> 6, lane = tid & 63;
  const int bm0 = blockIdx.x * 128, bn0 = blockIdx.y * 128;
  const int wm = (wave & 1) * 64, wn = (wave >> 1) * 64;
  const int kq = (lane >> 4) * 8;
  f32x4 acc[4][4];
#pragma unroll
  for (int i = 0; i < 4; ++i)
#pragma unroll
    for (int j = 0; j < 4; ++j) acc[i][j] = (f32x4){0.f, 0.f, 0.f, 0.f};

  const int srow = tid >> 2, soff = (tid & 3) * 8;
  const u16* Ag  = A + (size_t)(bm0 + srow) * Ka + soff;
  const u16* Ag2 = Ag + (size_t)64 * Ka;
  const u16* Bg  = B + (size_t)(bn0 + srow) * Ka + soff;
  const u16* Bg2 = Bg + (size_t)64 * Ka;
  u16* sA = As + wave * 512;
  u16* sB = Bs + wave * 512;

  for (int k0 = 0; k0 < Ka; k0 += 32) {
    __syncthreads();
    __builtin_amdgcn_global_load_lds((const __attribute__((address_space(1))) void*)(Ag + k0),
        (__attribute__((address_space(3))) void*)sA, 16, 0, 0);
    __builtin_amdgcn_global_load_lds((const __attribute__((address_space(1))) void*)(Ag2 + k0),
        (__attribute__((address_space(3))) void*)(sA + 2048), 16, 0, 0);
    __builtin_amdgcn_global_load_lds((const __attribute__((address_space(1))) void*)(Bg + k0),
        (__attribute__((address_space(3))) void*)sB, 16, 0, 0);
    __builtin_amdgcn_global_load_lds((const __attribute__((address_space(1))) void*)(Bg2 + k0),
        (__attribute__((address_space(3))) void*)(sB + 2048), 16, 0, 0);
    __syncthreads();
    s16x8 af[4], bf[4];
#pragma unroll
    for (int mi = 0; mi < 4; ++mi) af[mi] = *(const s16x8*)(As + (wm + mi * 16 + (lane & 15)) * 32 + kq);
#pragma unroll
    for (int ni = 0; ni < 4; ++ni) bf[ni] = *(const s16x8*)(Bs + (wn + ni * 16 + (lane & 15)) * 32 + kq);
#pragma unroll
    for (int mi = 0; mi < 4; ++mi)
#pragma unroll
      for (int ni = 0; ni < 4; ++ni)
        acc[mi][ni] = __builtin_amdgcn_mfma_f32_16x16x32_bf16(af[mi], bf[ni], acc[mi][ni], 0, 0, 0);
  }

#pragma unroll
  for (int mi = 0; mi < 4; ++mi)
#pragma unroll
    for (int r = 0; r < 4; ++r) {
      const int m = bm0 + wm + mi * 16 + (lane >> 4) * 4 + r;
#pragma unroll
      for (int ni = 0; ni < 4; ++ni) {
        const int n = bn0 + wn + ni * 16 + (lane & 15);
        float v = acc[mi][ni][r] + bias[n];
        if (EPI == 0) {
          const size_t off = (size_t)(n >> 11) * 16777216u
                           + (size_t)((m & 511) * 16 + (m >> 9)) * 2048 + (n & 2047);
          outp[off] = v;
        } else {
          v = (v > 0.f) ? v : 0.01f * v;
          outp[(size_t)m * N + n] = v;
        }
      }
    }
}

// ---------------------------------------------------------------- persistent biLSTM v3
// 32 WGs: dir = blk>>4; WG owns 32 hidden units; wave owns 8 units x ALL 4 gates
// (tile0 cols: gate i units 0-7 | gate f units 0-7; tile1: g | o). After MFMA,
// lane pairs (col, col^8) exchange gate halves via shfl_xor(8) and do pointwise
// in-register (duplicated). h ring: [dir][slot 0..3] of {hi[16][512], lo[16][512]}
// bf16 planes; staging = pure copy (16 atomic u64 -> ds_write_b64) into parity-
// double-buffered padded LDS ([batch][520]). Per-wave flags (64/dir): lane0
// RELEASE drains wave vmcnt. Yt stores after the flag. One __syncthreads/step.
__global__ __launch_bounds__(256, 1) void k_rec(const float* __restrict__ xg,
    const u16* __restrict__ WhiP, const int* __restrict__ lens, u16* __restrict__ Yt,
    u16* __restrict__ hbuf, u32* __restrict__ flags, int flagbase) {
  __shared__ u16 hs[2][16640];          // [parity][plane(2) x batch(16) x 520]
  const int tid = threadIdx.x, wave = tid >> 6, lane = tid & 63;
  const int dir = blockIdx.x >> 4, slice = blockIdx.x & 15, ubase = slice * 32;
  const int col = lane & 15, grp = lane >> 4;
  const int bq = grp * 4, kq = grp * 8;
  const int half = col >> 3, u7 = col & 7;
  const int ug = ubase + wave * 8 + u7;           // global unit in [0,512)

  // B fragments: tile j covers gate (2*j + half), unit ug. (likely AGPR-resident)
  s16x8 bfrag[2][16];
#pragma unroll
  for (int j = 0; j < 2; ++j) {
    const u16* wr = WhiP + ((size_t)dir * 2048 + (size_t)(2 * j + half) * 512 + ug) * 512 + kq;
#pragma unroll
    for (int kt = 0; kt < 16; ++kt) bfrag[j][kt] = *(const s16x8*)(wr + kt * 32);
  }

  int lenv[4];
#pragma unroll
  for (int r = 0; r < 4; ++r) lenv[r] = lens[bq + r];
  float c_[4] = {0.f, 0.f, 0.f, 0.f}, h_[4] = {0.f, 0.f, 0.f, 0.f};

  const float* xgp = xg + (size_t)dir * 16777216u;
  u32* myflags = flags + dir * 64;
  u16* hbase = hbuf + (size_t)dir * 65536;        // 4 slots x 16384 u16

  const int cg0 = half * 512 + ug;                // xg col, tile0 (gates i/f)
  const int cg1 = cg0 + 1024;                     // tile1 (gates g/o)
  const int sp = tid >> 7, sr = tid & 127;        // staging: plane, then 128B chunk
  const int sb = sr >> 3, se = sr & 7;
  const bool st = (half == 0) && ((u7 & 1) == 0); // storing lane (even unit, half 0)

  for (int s = 0; s < 512; ++s) {
    const int t = dir ? (511 - s) : s;
    // xg prefetch (in flight during poll+staging)
    const float* xr = xgp + ((size_t)t * 16 + bq) * 2048;
    f32x4 a0, a1;
#pragma unroll
    for (int r = 0; r < 4; ++r) { a0[r] = xr[r * 2048 + cg0]; a1[r] = xr[r * 2048 + cg1]; }

    if (s > 0) {
      const u32 tgt = (u32)(flagbase + s);
      bool ok;
      do {                                         // one flag per lane, 64 waves/dir
        u32 f = __hip_atomic_load(&myflags[lane], __ATOMIC_RELAXED, __HIP_MEMORY_SCOPE_AGENT);
        ok = (~__ballot(f >= tgt)) == 0ull;
      } while (!ok);
      // stage 128B of the hi/lo planes: pure copy, no de-interleave
      const u64* src = (const u64*)(hbase + (size_t)(s & 3) * 16384
                                    + sp * 8192 + sb * 512 + se * 64);
      u64 wv[16];
#pragma unroll
      for (int i = 0; i < 16; ++i)
        wv[i] = __hip_atomic_load(src + i, __ATOMIC_RELAXED, __HIP_MEMORY_SCOPE_AGENT);
      u64* dst = (u64*)(hs[s & 1] + sp * 8320 + sb * 520 + se * 64);
#pragma unroll
      for (int i = 0; i < 16; ++i) dst[i] = wv[i];
    }
    __syncthreads();                               // staging -> ds_read (only barrier)
    if (s > 0) {
      const u16* hh = hs[s & 1] + col * 520 + kq;  // A row = batch = col
      const u16* hl = hh + 8320;
      f32x4 l0 = (f32x4){0.f, 0.f, 0.f, 0.f}, l1 = (f32x4){0.f, 0.f, 0.f, 0.f};
#pragma unroll
      for (int kt = 0; kt < 16; ++kt) {
        s16x8 ah = *(const s16x8*)(hh + kt * 32);
        s16x8 al = *(const s16x8*)(hl + kt * 32);
        a0 = __builtin_amdgcn_mfma_f32_16x16x32_bf16(ah, bfrag[0][kt], a0, 0, 0, 0);
        a1 = __builtin_amdgcn_mfma_f32_16x16x32_bf16(ah, bfrag[1][kt], a1, 0, 0, 0);
        l0 = __builtin_amdgcn_mfma_f32_16x16x32_bf16(al, bfrag[0][kt], l0, 0, 0, 0);
        l1 = __builtin_amdgcn_mfma_f32_16x16x32_bf16(al, bfrag[1][kt], l1, 0, 0, 0);
      }
      a0 += l0; a1 += l1;
    }

    // in-wave gate exchange + pointwise (duplicated across lane pairs col<->col^8)
    float yh[4], ynb[4];
    u32 hiw[4], low[4];
#pragma unroll
    for (int r = 0; r < 4; ++r) {
      const float oth0 = __shfl_xor(a0[r], 8, 64);
      const float oth1 = __shfl_xor(a1[r], 8, 64);
      const float gi = half ? oth0 : a0[r];
      const float gf = half ? a0[r] : oth0;
      const float gg = half ? oth1 : a1[r];
      const float go = half ? a1[r] : oth1;
      const float ii = 1.f / (1.f + __expf(-gi));
      const float ff = 1.f / (1.f + __expf(-gf));
      const float gz = 1.f - 2.f / (__expf(2.f * gg) + 1.f);   // tanh
      const float oo = 1.f / (1.f + __expf(-go));
      const float cn = ff * c_[r] + ii * gz;
      const float hn = oo * (1.f - 2.f / (__expf(2.f * cn) + 1.f));
      const bool mk = (t < lenv[r]);
      c_[r] = mk ? cn : c_[r];
      h_[r] = mk ? hn : h_[r];
      yh[r] = mk ? hn : 0.f;
    }
#pragma unroll
    for (int r = 0; r < 4; ++r) {                  // pair units (ug, ug+1)
      const float hb = __shfl_xor(h_[r], 1, 64);
      const u16 mh = f2b(h_[r]), nh = f2b(hb);
      const u16 ml = f2b(h_[r] - b2f(mh)), nl = f2b(hb - b2f(nh));
      hiw[r] = (u32)mh | ((u32)nh << 16);
      low[r] = (u32)ml | ((u32)nl << 16);
      ynb[r] = __shfl_xor(yh[r], 1, 64);
    }
    if (s < 511) {
      if (st) {                                    // publish carried h, hi/lo planes
        u16* slot = hbase + (size_t)((s + 1) & 3) * 16384;
#pragma unroll
        for (int r = 0; r < 4; ++r) {
          u32* dh = (u32*)(slot + (size_t)(bq + r) * 512 + ug);
          u32* dl = (u32*)(slot + 8192 + (size_t)(bq + r) * 512 + ug);
          __hip_atomic_store(dh, hiw[r], __ATOMIC_RELAXED, __HIP_MEMORY_SCOPE_AGENT);
          __hip_atomic_store(dl, low[r], __ATOMIC_RELAXED, __HIP_MEMORY_SCOPE_AGENT);
        }
      }
      if (lane == 0)                               // wave-level release: drains vmcnt
        __hip_atomic_store(&myflags[slice * 4 + wave], (u32)(flagbase + s + 1),
                           __ATOMIC_RELEASE, __HIP_MEMORY_SCOPE_AGENT);
    }
    __builtin_amdgcn_sched_barrier(0);             // keep Yt stores after the flag
    if (st) {                                      // next-layer A-triple output
#pragma unroll
      for (int r = 0; r < 4; ++r) {
        u32 w0, w1, w2;
        packA3(yh[r], ynb[r], w0, w1, w2);
        u32* yp = (u32*)(Yt + (size_t)((bq + r) * 512 + t) * 3072
                         + 3 * (size_t)(dir * 512 + ug));
        yp[0] = w0; yp[1] = w1; yp[2] = w2;
      }
    }
  }
}

// ---------------------------------------------------------------- head: out = a2 @ W3^T + b3
__global__ __launch_bounds__(256) void k_head(const float* __restrict__ a2,
    const float* __restrict__ W3, const float* __restrict__ b3, float* __restrict__ out) {
  const int m = (blockIdx.x * 256 + threadIdx.x) >> 6;   // wave per row
  const int lane = threadIdx.x & 63;
  const float* row = a2 + (size_t)m * 1024;
  float s[5] = {0.f, 0.f, 0.f, 0.f, 0.f};
  for (int j = lane; j < 1024; j += 64) {
    const float v = row[j];
#pragma unroll
    for (int c = 0; c < 5; ++c) s[c] += v * W3[c * 1024 + j];
  }
#pragma unroll
  for (int c = 0; c < 5; ++c)
    for (int off = 32; off > 0; off >>= 1) s[c] += __shfl_down(s[c], off, 64);
  if (lane == 0)
#pragma unroll
    for (int c = 0; c < 5; ++c) out[(size_t)m * 5 + c] = s[c] + b3[c];   // fp32 output
}

// ---------------------------------------------------------------- launch
extern "C" void kernel_launch(void* const* d_in, const int* in_sizes, int n_in,
                              void* d_out, int out_size, void* d_ws, size_t ws_size,
                              hipStream_t stream) {
  const int*   x    = (const int*)d_in[0];
  const int*   lens = (const int*)d_in[1];
  const float* lang = (const float*)d_in[2];
  const float* emb  = (const float*)d_in[3];
  const float* Wih  = (const float*)d_in[4];   // [2][2][2048][1024]
  const float* Whh  = (const float*)d_in[5];   // [2][2][2048][512]
  const float* bih  = (const float*)d_in[6];
  const float* bhh  = (const float*)d_in[7];
  const float* W1   = (const float*)d_in[8];
  const float* b1   = (const float*)d_in[9];
  const float* W2   = (const float*)d_in[10];
  const float* b2   = (const float*)d_in[11];
  const float* W3   = (const float*)d_in[12];
  const float* b3   = (const float*)d_in[13];
  float* out = (float*)d_out;
  char* ws = (char*)d_ws;

  // workspace (~223 MiB). act overlays xg (xg dead after k_rec layer 1).
  float* xg     = (float*)(ws + 0);             // [2][8192][2048] f32  134,217,728
  float* act    = (float*)(ws + 0);             //  [8192][1024] f32 overlay
  u16*   A3     = (u16*)(ws + 134217728);       //  [8192][3072] u16     50,331,648
  u16*   wb3    = (u16*)(ws + 184549376);       //  [4096][3072] u16     25,165,824
  u16*   whh_hi = (u16*)(ws + 209715200);       //  [2][2][2048][512]     8,388,608
  u16*   w3b    = (u16*)(ws + 226492416);       //  [1024][3072] u16      6,291,456
  u16*   hbuf   = (u16*)(ws + 232783872);       //  [2][4][32KB] ring       262,144
  float* bsum   = (float*)(ws + 233046016);     //  [2][2][2048]             32,768
  u32*   flags  = (u32*)(ws + 233078784);       //  [2][64]                    512

  hipMemsetAsync(flags, 0, 512, stream);
  k_prepb<<<32, 256, 0, stream>>>(bih, bhh, bsum);
  k_prepwh<<<4096, 256, 0, stream>>>(Whh, whh_hi);
  k_embed<<<8192, 256, 0, stream>>>(x, lang, emb, A3);

  // layer 0
  k_prepw<<<4096, 256, 0, stream>>>(Wih, wb3, 1048576);
  k_gemm<0><<<dim3(64, 32), 256, 0, stream>>>(A3, wb3, bsum, xg, 3072, 4096);
  k_rec<<<32, 256, 0, stream>>>(xg, whh_hi, lens, A3, hbuf, flags, 0);
  // layer 1
  k_prepw<<<4096, 256, 0, stream>>>(Wih + 4194304, wb3, 1048576);
  k_gemm<0><<<dim3(64, 32), 256, 0, stream>>>(A3, wb3, bsum + 4096, xg, 3072, 4096);
  k_rec<<<32, 256, 0, stream>>>(xg, whh_hi + 2097152, lens, A3, hbuf, flags, 512);
  // head
  k_prepw<<<1024, 256, 0, stream>>>(W1, w3b, 262144);
  k_gemm<1><<<dim3(64, 8), 256, 0, stream>>>(A3, w3b, b1, act, 3072, 1024);
  k_tri<<<8192, 256, 0, stream>>>(act, A3);
  k_prepw<<<1024, 256, 0, stream>>>(W2, w3b, 262144);
  k_gemm<1><<<dim3(64, 8), 256, 0, stream>>>(A3, w3b, b2, act, 3072, 1024);
  k_head<<<2048, 256, 0, stream>>>(act, W3, b3, out);
}

// Round 3
// 5465.280 us; speedup vs baseline: 2.6547x; 1.9866x over previous
//
#include <hip/hip_runtime.h>

// LangModelWithLSTM on MI355X (gfx950). fp32 inputs, fp32 output.
// embed-concat -> [xg GEMM -> persistent biLSTM recurrence] x2 -> MLP head.
// fp32 accuracy via bf16 MFMA with hi/lo splitting:
//   GEMMs: K-tripled streams  A={a_hi,a_lo,a_hi} x B={w_hi,w_hi,w_lo}
//   recurrence: (h_hi + h_lo) x W_hi   (W_lo term negligible)
// Cross-WG h exchange v4 (v1 structure + two surgical fixes):
//   - hbuf holds separate hi/lo bf16 PLANES [dir][slot][plane][batch][512];
//     producer (pp,bb) mapping writes 2 u32/thread -> full 64B lines per wave;
//     consumer staging is a PURE COPY (16 atomic u64 -> ds_write_b64), no
//     de-interleave VALU chain on the critical path.
//   - Yt (next-layer) stores issued AFTER the flag release; their HBM drain
//     happens at the NEXT step's first barrier, overlapped with poll+load.
//   - otherwise identical to the 2300us/k_rec v1: 3 barriers, 16 WG flags/dir
//     (one 64B line), lane<16 poll + s_sleep(1), padded hs rows (520 u16).
// B=16, S=512, H=512, D_IN=1024, 4H=2048, HID=1024, C=5, L=2 bidirectional.

typedef unsigned short u16;
typedef unsigned int   u32;
typedef unsigned long long u64;
typedef short s16x8 __attribute__((ext_vector_type(8)));   // MFMA A/B frag (8 bf16)
typedef float f32x4 __attribute__((ext_vector_type(4)));   // MFMA accumulator

__device__ __forceinline__ float b2f(u16 h) { return __uint_as_float(((u32)h) << 16); }
__device__ __forceinline__ u16 f2b(float x) {            // round-to-nearest-even
  u32 u = __float_as_uint(x);
  return (u16)((u + 0x7fffu + ((u >> 16) & 1u)) >> 16);
}
// A-side pair -> 3 u32 words: u16 stream {h0,l0,h0, h1,l1,h1}
__device__ __forceinline__ void packA3(float v0, float v1, u32& w0, u32& w1, u32& w2) {
  u16 h0 = f2b(v0), h1 = f2b(v1);
  u16 l0 = f2b(v0 - b2f(h0)), l1 = f2b(v1 - b2f(h1));
  w0 = (u32)h0 | ((u32)l0 << 16);
  w1 = (u32)h0 | ((u32)h1 << 16);
  w2 = (u32)l1 | ((u32)h1 << 16);
}
// B-side pair -> 3 u32 words: u16 stream {h0,h0,l0, h1,h1,l1}
__device__ __forceinline__ void packB3(float v0, float v1, u32& w0, u32& w1, u32& w2) {
  u16 h0 = f2b(v0), h1 = f2b(v1);
  u16 l0 = f2b(v0 - b2f(h0)), l1 = f2b(v1 - b2f(h1));
  w0 = (u32)h0 | ((u32)h0 << 16);
  w1 = (u32)l0 | ((u32)h1 << 16);
  w2 = (u32)h1 | ((u32)l1 << 16);
}

// ---------------------------------------------------------------- embed -> A3 triple
__global__ __launch_bounds__(256) void k_embed(const int* __restrict__ x,
    const float* __restrict__ lang, const float* __restrict__ emb, u16* __restrict__ A3) {
  const int m = blockIdx.x;                  // 8192 rows = b*512+s
  const int k = threadIdx.x * 4;             // 4 source elems
  const float* src = (k < 768) ? (lang + (size_t)m * 768 + k)
                               : (emb + (size_t)x[m] * 256 + (k - 768));
  float4 v = *(const float4*)src;
  u32 w0, w1, w2, w3, w4, w5;
  packA3(v.x, v.y, w0, w1, w2);
  packA3(v.z, v.w, w3, w4, w5);
  uint2* dst = (uint2*)(A3 + (size_t)m * 3072 + 3 * k);
  dst[0] = make_uint2(w0, w1); dst[1] = make_uint2(w2, w3); dst[2] = make_uint2(w4, w5);
}

// ---------------------------------------------------------------- weight preps
// fp32 W [rows][1024] -> triple [rows][3072]; one quad per thread.
__global__ __launch_bounds__(256) void k_prepw(const float* __restrict__ W,
    u16* __restrict__ W3, int nq) {
  const int idx = blockIdx.x * 256 + threadIdx.x;
  if (idx >= nq) return;
  const int base = idx * 4, row = base >> 10, k = base & 1023;
  float4 v = *(const float4*)(W + base);
  u32 w0, w1, w2, w3, w4, w5;
  packB3(v.x, v.y, w0, w1, w2);
  packB3(v.z, v.w, w3, w4, w5);
  uint2* dst = (uint2*)(W3 + (size_t)row * 3072 + 3 * k);
  dst[0] = make_uint2(w0, w1); dst[1] = make_uint2(w2, w3); dst[2] = make_uint2(w4, w5);
}
// Whh fp32 flat [4194304] -> hi bf16 plane (lo plane dropped in recurrence)
__global__ __launch_bounds__(256) void k_prepwh(const float* __restrict__ W,
    u16* __restrict__ hi) {
  const int idx = blockIdx.x * 256 + threadIdx.x;   // 1,048,576 quads
  const int base = idx * 4;
  float4 v = *(const float4*)(W + base);
  float vv[4] = {v.x, v.y, v.z, v.w};
  u16 h[4];
#pragma unroll
  for (int i = 0; i < 4; ++i) h[i] = f2b(vv[i]);
  *(uint2*)(hi + base) = make_uint2((u32)h[0] | ((u32)h[1] << 16), (u32)h[2] | ((u32)h[3] << 16));
}
__global__ __launch_bounds__(256) void k_prepb(const float* __restrict__ bih,
    const float* __restrict__ bhh, float* __restrict__ bsum) {
  const int tid = blockIdx.x * 256 + threadIdx.x;   // 8192
  bsum[tid] = bih[tid] + bhh[tid];
}
// act fp32 [8192][1024] -> A3 triple
__global__ __launch_bounds__(256) void k_tri(const float* __restrict__ act, u16* __restrict__ A3) {
  const int idx = blockIdx.x * 256 + threadIdx.x;   // 2,097,152 quads
  const int base = idx * 4, row = base >> 10, k = base & 1023;
  float4 v = *(const float4*)(act + base);
  u32 w0, w1, w2, w3, w4, w5;
  packA3(v.x, v.y, w0, w1, w2);
  packA3(v.z, v.w, w3, w4, w5);
  uint2* dst = (uint2*)(A3 + (size_t)row * 3072 + 3 * k);
  dst[0] = make_uint2(w0, w1); dst[1] = make_uint2(w2, w3); dst[2] = make_uint2(w4, w5);
}

// ---------------------------------------------------------------- GEMM (m97 style)
// C[m][n] = sum_k A[m][k]*B[n][k] + bias[n]. 128x128 tile, BK=32, 4 waves.
// EPI=0: fp32 -> xg layout [dir=n>>11][(s*16+b)][n&2047]  (N==4096)
// EPI=1: fp32 [m][N] + leaky-relu -> act.
template <int EPI>
__global__ __launch_bounds__(256) void k_gemm(const u16* __restrict__ A,
    const u16* __restrict__ B, const float* __restrict__ bias, float* __restrict__ outp,
    int Ka, int N) {
  __shared__ u16 As[4096];   // [128][32]
  __shared__ u16 Bs[4096];
  const int tid = threadIdx.x, wave = tid >> 6, lane = tid & 63;
  const int bm0 = blockIdx.x * 128, bn0 = blockIdx.y * 128;
  const int wm = (wave & 1) * 64, wn = (wave >> 1) * 64;
  const int kq = (lane >> 4) * 8;
  f32x4 acc[4][4];
#pragma unroll
  for (int i = 0; i < 4; ++i)
#pragma unroll
    for (int j = 0; j < 4; ++j) acc[i][j] = (f32x4){0.f, 0.f, 0.f, 0.f};

  const int srow = tid >> 2, soff = (tid & 3) * 8;
  const u16* Ag  = A + (size_t)(bm0 + srow) * Ka + soff;
  const u16* Ag2 = Ag + (size_t)64 * Ka;
  const u16* Bg  = B + (size_t)(bn0 + srow) * Ka + soff;
  const u16* Bg2 = Bg + (size_t)64 * Ka;
  u16* sA = As + wave * 512;
  u16* sB = Bs + wave * 512;

  for (int k0 = 0; k0 < Ka; k0 += 32) {
    __syncthreads();
    __builtin_amdgcn_global_load_lds((const __attribute__((address_space(1))) void*)(Ag + k0),
        (__attribute__((address_space(3))) void*)sA, 16, 0, 0);
    __builtin_amdgcn_global_load_lds((const __attribute__((address_space(1))) void*)(Ag2 + k0),
        (__attribute__((address_space(3))) void*)(sA + 2048), 16, 0, 0);
    __builtin_amdgcn_global_load_lds((const __attribute__((address_space(1))) void*)(Bg + k0),
        (__attribute__((address_space(3))) void*)sB, 16, 0, 0);
    __builtin_amdgcn_global_load_lds((const __attribute__((address_space(1))) void*)(Bg2 + k0),
        (__attribute__((address_space(3))) void*)(sB + 2048), 16, 0, 0);
    __syncthreads();
    s16x8 af[4], bf[4];
#pragma unroll
    for (int mi = 0; mi < 4; ++mi) af[mi] = *(const s16x8*)(As + (wm + mi * 16 + (lane & 15)) * 32 + kq);
#pragma unroll
    for (int ni = 0; ni < 4; ++ni) bf[ni] = *(const s16x8*)(Bs + (wn + ni * 16 + (lane & 15)) * 32 + kq);
#pragma unroll
    for (int mi = 0; mi < 4; ++mi)
#pragma unroll
      for (int ni = 0; ni < 4; ++ni)
        acc[mi][ni] = __builtin_amdgcn_mfma_f32_16x16x32_bf16(af[mi], bf[ni], acc[mi][ni], 0, 0, 0);
  }

#pragma unroll
  for (int mi = 0; mi < 4; ++mi)
#pragma unroll
    for (int r = 0; r < 4; ++r) {
      const int m = bm0 + wm + mi * 16 + (lane >> 4) * 4 + r;
#pragma unroll
      for (int ni = 0; ni < 4; ++ni) {
        const int n = bn0 + wn + ni * 16 + (lane & 15);
        float v = acc[mi][ni][r] + bias[n];
        if (EPI == 0) {
          const size_t off = (size_t)(n >> 11) * 16777216u
                           + (size_t)((m & 511) * 16 + (m >> 9)) * 2048 + (n & 2047);
          outp[off] = v;
        } else {
          v = (v > 0.f) ? v : 0.01f * v;
          outp[(size_t)m * N + n] = v;
        }
      }
    }
}

// ---------------------------------------------------------------- persistent biLSTM v4
// 32 WGs: dir = blk>>4; each WG owns 32 hidden units (4 gates x 16 batches).
// Wave g = gate g, 2 column-tiles of 16 units. W_hi frags pinned in VGPRs.
// h ring: [dir][slot 0..3][plane hi/lo][batch 16][512 u16] (32KB/slot).
// Producer: thread (pp,bb) stores 2 u32 (hi,lo) -> per wave, per batch row,
// 16 threads x 4B = one full 64B line. Consumer staging: PURE COPY, thread
// (sp,srow,soff) does 16 atomic u64 loads (64B stride) -> ds_write_b64 into
// padded hs rows (520 u16). 16 WG flags/dir (one 64B line), lane<16 poll +
// s_sleep(1). Yt stores AFTER the flag (drain deferred to next step's B1).
__global__ __launch_bounds__(256, 1) void k_rec(const float* __restrict__ xg,
    const u16* __restrict__ WhiP, const int* __restrict__ lens, u16* __restrict__ Yt,
    u16* __restrict__ hbuf, u32* __restrict__ flags, int flagbase) {
  __shared__ u16 hs[2 * 16 * 520];     // [plane hi/lo][batch][512+8 pad]
  __shared__ float gx[4][16][33];      // [gate][batch][32 units + pad]
  const int tid = threadIdx.x, wave = tid >> 6, lane = tid & 63;
  const int dir = blockIdx.x >> 4, slice = blockIdx.x & 15, ubase = slice * 32;
  const int kq = (lane >> 4) * 8;
  const int col = lane & 15;
  const int bq = (lane >> 4) * 4;

  s16x8 bfrag[2][16];                  // W_hi rows g = wave*512 + ubase + j*16 + col
#pragma unroll
  for (int j = 0; j < 2; ++j) {
    const u16* wr = WhiP + ((size_t)dir * 2048 + wave * 512 + ubase + j * 16 + col) * 512 + kq;
#pragma unroll
    for (int kt = 0; kt < 16; ++kt) bfrag[j][kt] = *(const s16x8*)(wr + kt * 32);
  }
  const int pp = tid & 15, bb = tid >> 4;   // pointwise: units 2pp,2pp+1, batch bb
  const int len_b = lens[bb];
  float c0 = 0.f, h0v = 0.f, c1 = 0.f, h1v = 0.f;
  const float* xgp = xg + (size_t)dir * 16777216u;
  u32* myflags = flags + dir * 16;
  // staging thread coords: plane sp, batch row srow, 64B chunk soff
  const int sp = tid >> 7, srow = (tid & 127) >> 3, soff = tid & 7;
  const u64* hb64 = (const u64*)hbuf + (size_t)dir * 16384;   // 4 slots x 4096 u64

  for (int s = 0; s < 512; ++s) {
    const int t = dir ? (511 - s) : s;
    // prefetch this step's xg (in flight during poll); acc rows b=bq+r, cols j*16+col
    const float* xr = xgp + ((size_t)t * 16 + bq) * 2048 + wave * 512 + ubase + col;
    f32x4 a0, a1;
    a0[0] = xr[0];  a0[1] = xr[2048]; a0[2] = xr[4096]; a0[3] = xr[6144];
    a1[0] = xr[16]; a1[1] = xr[2064]; a1[2] = xr[4112]; a1[3] = xr[6160];

    if (s > 0) {
      const u32 tgt = (u32)(flagbase + s);
      bool ok;
      do {                                             // 16-flag poll: one 64B line
        u32 f = 0xffffffffu;
        if (lane < 16) f = __hip_atomic_load(&myflags[lane], __ATOMIC_RELAXED, __HIP_MEMORY_SCOPE_AGENT);
        ok = (~__ballot(f >= tgt)) == 0ull;
        if (!ok) __builtin_amdgcn_s_sleep(1);
      } while (!ok);
      // pure-copy staging: 16 atomic u64 loads (64B stride) -> ds_write_b64
      const u64* src = hb64 + (size_t)(s & 3) * 4096 + sp * 2048 + srow * 128 + soff;
      u64 wv[16];
#pragma unroll
      for (int i = 0; i < 16; ++i)
        wv[i] = __hip_atomic_load(src + i * 8, __ATOMIC_RELAXED, __HIP_MEMORY_SCOPE_AGENT);
      u64* drow = (u64*)(hs + sp * 8320 + srow * 520);
#pragma unroll
      for (int i = 0; i < 16; ++i) drow[soff + i * 8] = wv[i];
    }
    __syncthreads();
    if (s > 0) {
      f32x4 l0 = (f32x4){0.f, 0.f, 0.f, 0.f}, l1 = (f32x4){0.f, 0.f, 0.f, 0.f};
      const u16* hh = hs + col * 520 + kq;     // A row = batch = col
      const u16* hl = hh + 8320;
#pragma unroll
      for (int kt = 0; kt < 16; ++kt) {
        s16x8 ah = *(const s16x8*)(hh + kt * 32);
        s16x8 al = *(const s16x8*)(hl + kt * 32);
        a0 = __builtin_amdgcn_mfma_f32_16x16x32_bf16(ah, bfrag[0][kt], a0, 0, 0, 0);
        a1 = __builtin_amdgcn_mfma_f32_16x16x32_bf16(ah, bfrag[1][kt], a1, 0, 0, 0);
        l0 = __builtin_amdgcn_mfma_f32_16x16x32_bf16(al, bfrag[0][kt], l0, 0, 0, 0);
        l1 = __builtin_amdgcn_mfma_f32_16x16x32_bf16(al, bfrag[1][kt], l1, 0, 0, 0);
      }
      a0 += l0; a1 += l1;
    }
#pragma unroll
    for (int r = 0; r < 4; ++r) {
      gx[wave][bq + r][col] = a0[r];
      gx[wave][bq + r][16 + col] = a1[r];
    }
    __syncthreads();

    const int u0 = 2 * pp, u1 = u0 + 1;
    const float gi0 = gx[0][bb][u0], gf0 = gx[1][bb][u0], gg0 = gx[2][bb][u0], go0 = gx[3][bb][u0];
    const float gi1 = gx[0][bb][u1], gf1 = gx[1][bb][u1], gg1 = gx[2][bb][u1], go1 = gx[3][bb][u1];
    const float ii0 = 1.f / (1.f + __expf(-gi0)),  ii1 = 1.f / (1.f + __expf(-gi1));
    const float ff0 = 1.f / (1.f + __expf(-gf0)),  ff1 = 1.f / (1.f + __expf(-gf1));
    const float gz0 = 1.f - 2.f / (__expf(2.f * gg0) + 1.f);   // tanh
    const float gz1 = 1.f - 2.f / (__expf(2.f * gg1) + 1.f);
    const float oo0 = 1.f / (1.f + __expf(-go0)),  oo1 = 1.f / (1.f + __expf(-go1));
    const float cn0 = ff0 * c0 + ii0 * gz0,        cn1 = ff1 * c1 + ii1 * gz1;
    const float hn0 = oo0 * (1.f - 2.f / (__expf(2.f * cn0) + 1.f));
    const float hn1 = oo1 * (1.f - 2.f / (__expf(2.f * cn1) + 1.f));
    const bool mk = (t < len_b);
    c0 = mk ? cn0 : c0;  h0v = mk ? hn0 : h0v;
    c1 = mk ? cn1 : c1;  h1v = mk ? hn1 : h1v;
    const float y0 = mk ? hn0 : 0.f, y1 = mk ? hn1 : 0.f;

    if (s < 511) {                       // publish carried h pair to plane slot (s+1)&3
      const u16 s0h = f2b(h0v), s0l = f2b(h0v - b2f(s0h));
      const u16 s1h = f2b(h1v), s1l = f2b(h1v - b2f(s1h));
      u16* slot = hbuf + (size_t)dir * 65536 + (size_t)((s + 1) & 3) * 16384;
      u32* dh = (u32*)(slot + (size_t)bb * 512 + ubase) + pp;          // hi plane
      u32* dl = (u32*)(slot + 8192 + (size_t)bb * 512 + ubase) + pp;   // lo plane
      __hip_atomic_store(dh, (u32)s0h | ((u32)s1h << 16), __ATOMIC_RELAXED, __HIP_MEMORY_SCOPE_AGENT);
      __hip_atomic_store(dl, (u32)s0l | ((u32)s1l << 16), __ATOMIC_RELAXED, __HIP_MEMORY_SCOPE_AGENT);
    }
    __syncthreads();                     // all waves drain vmcnt before flag
    if (tid == 0)
      __hip_atomic_store(&myflags[slice], (u32)(flagbase + s + 1),
                         __ATOMIC_RELEASE, __HIP_MEMORY_SCOPE_AGENT);
    __builtin_amdgcn_sched_barrier(0);   // keep Yt stores after the flag

    // output: next-layer A-triple {hi,lo,hi} of y = h_new*mask (unit pair -> 12B);
    // these HBM stores drain at the NEXT step's first barrier (overlapped).
    u32 w0, w1, w2;
    packA3(y0, y1, w0, w1, w2);
    const int ug = dir * 512 + ubase + u0;               // even
    u32* yp = (u32*)(Yt + (size_t)(bb * 512 + t) * 3072 + 3 * ug);
    yp[0] = w0; yp[1] = w1; yp[2] = w2;
  }
}

// ---------------------------------------------------------------- head: out = a2 @ W3^T + b3
__global__ __launch_bounds__(256) void k_head(const float* __restrict__ a2,
    const float* __restrict__ W3, const float* __restrict__ b3, float* __restrict__ out) {
  const int m = (blockIdx.x * 256 + threadIdx.x) >> 6;   // wave per row
  const int lane = threadIdx.x & 63;
  const float* row = a2 + (size_t)m * 1024;
  float s[5] = {0.f, 0.f, 0.f, 0.f, 0.f};
  for (int j = lane; j < 1024; j += 64) {
    const float v = row[j];
#pragma unroll
    for (int c = 0; c < 5; ++c) s[c] += v * W3[c * 1024 + j];
  }
#pragma unroll
  for (int c = 0; c < 5; ++c)
    for (int off = 32; off > 0; off >>= 1) s[c] += __shfl_down(s[c], off, 64);
  if (lane == 0)
#pragma unroll
    for (int c = 0; c < 5; ++c) out[(size_t)m * 5 + c] = s[c] + b3[c];   // fp32 output
}

// ---------------------------------------------------------------- launch
extern "C" void kernel_launch(void* const* d_in, const int* in_sizes, int n_in,
                              void* d_out, int out_size, void* d_ws, size_t ws_size,
                              hipStream_t stream) {
  const int*   x    = (const int*)d_in[0];
  const int*   lens = (const int*)d_in[1];
  const float* lang = (const float*)d_in[2];
  const float* emb  = (const float*)d_in[3];
  const float* Wih  = (const float*)d_in[4];   // [2][2][2048][1024]
  const float* Whh  = (const float*)d_in[5];   // [2][2][2048][512]
  const float* bih  = (const float*)d_in[6];
  const float* bhh  = (const float*)d_in[7];
  const float* W1   = (const float*)d_in[8];
  const float* b1   = (const float*)d_in[9];
  const float* W2   = (const float*)d_in[10];
  const float* b2   = (const float*)d_in[11];
  const float* W3   = (const float*)d_in[12];
  const float* b3   = (const float*)d_in[13];
  float* out = (float*)d_out;
  char* ws = (char*)d_ws;

  // workspace (~223 MiB). act overlays xg (xg dead after k_rec layer 1).
  float* xg     = (float*)(ws + 0);             // [2][8192][2048] f32  134,217,728
  float* act    = (float*)(ws + 0);             //  [8192][1024] f32 overlay
  u16*   A3     = (u16*)(ws + 134217728);       //  [8192][3072] u16     50,331,648
  u16*   wb3    = (u16*)(ws + 184549376);       //  [4096][3072] u16     25,165,824
  u16*   whh_hi = (u16*)(ws + 209715200);       //  [2][2][2048][512]     8,388,608
  u16*   w3b    = (u16*)(ws + 226492416);       //  [1024][3072] u16      6,291,456
  u16*   hbuf   = (u16*)(ws + 232783872);       //  [2][4][32KB] ring       262,144
  float* bsum   = (float*)(ws + 233046016);     //  [2][2][2048]             32,768
  u32*   flags  = (u32*)(ws + 233078784);       //  [2][16]                     256

  hipMemsetAsync(flags, 0, 256, stream);
  k_prepb<<<32, 256, 0, stream>>>(bih, bhh, bsum);
  k_prepwh<<<4096, 256, 0, stream>>>(Whh, whh_hi);
  k_embed<<<8192, 256, 0, stream>>>(x, lang, emb, A3);

  // layer 0
  k_prepw<<<4096, 256, 0, stream>>>(Wih, wb3, 1048576);
  k_gemm<0><<<dim3(64, 32), 256, 0, stream>>>(A3, wb3, bsum, xg, 3072, 4096);
  k_rec<<<32, 256, 0, stream>>>(xg, whh_hi, lens, A3, hbuf, flags, 0);
  // layer 1
  k_prepw<<<4096, 256, 0, stream>>>(Wih + 4194304, wb3, 1048576);
  k_gemm<0><<<dim3(64, 32), 256, 0, stream>>>(A3, wb3, bsum + 4096, xg, 3072, 4096);
  k_rec<<<32, 256, 0, stream>>>(xg, whh_hi + 2097152, lens, A3, hbuf, flags, 512);
  // head
  k_prepw<<<1024, 256, 0, stream>>>(W1, w3b, 262144);
  k_gemm<1><<<dim3(64, 8), 256, 0, stream>>>(A3, w3b, b1, act, 3072, 1024);
  k_tri<<<8192, 256, 0, stream>>>(act, A3);
  k_prepw<<<1024, 256, 0, stream>>>(W2, w3b, 262144);
  k_gemm<1><<<dim3(64, 8), 256, 0, stream>>>(A3, w3b, b2, act, 3072, 1024);
  k_head<<<2048, 256, 0, stream>>>(act, W3, b3, out);
}

// Round 4
// 3846.199 us; speedup vs baseline: 3.7722x; 1.4210x over previous
//
#include <hip/hip_runtime.h>

// LangModelWithLSTM on MI355X (gfx950). fp32 inputs, fp32 output.
// embed-concat -> [xg GEMM -> persistent biLSTM recurrence] x2 -> MLP head.
// fp32 accuracy via bf16 MFMA with hi/lo splitting:
//   GEMMs: K-tripled streams  A={a_hi,a_lo,a_hi} x B={w_hi,w_hi,w_lo}
//   recurrence: (h_hi + h_lo) x W_hi   (W_lo term negligible)
// Cross-WG h exchange v5: DATA-AS-FLAG sentinel protocol.
//   - per-step unique buffers (no ring, no ABA): slot g = dir*512 + step,
//     each 32KB = {hi[16][512], lo[16][512]} bf16 planes. Regions pre-filled
//     with 0x7F bytes (u32 0x7F7F7F7F = bf16 exp 254 = impossible for |h|<1).
//   - producer: after pointwise, 2 relaxed AGENT u32 stores. NO drain barrier,
//     NO flag, NO release ordering. Yt stores after.
//   - consumer: staging thread polls ITS 16 u64 until no u32 == sentinel,
//     then ds_write_b64 to LDS. One MALL RT on the critical path (was 3).
//   - 2 intra-WG barriers/step (B1 staging->ds_read, B2 gx write->read);
//     single-buffered hs/gx safe: B1/B2 separate the hazards across steps.
//   - slots live in the wb3 region (dead during k_rec) + the 8.39MB hole:
//     g<768 -> stepA + g*32KB ; g>=768 -> stepB + (g-768)*32KB. memset 0x7F
//     between each GEMM and k_rec (stream-ordered).
// B=16, S=512, H=512, D_IN=1024, 4H=2048, HID=1024, C=5, L=2 bidirectional.

typedef unsigned short u16;
typedef unsigned int   u32;
typedef unsigned long long u64;
typedef short s16x8 __attribute__((ext_vector_type(8)));   // MFMA A/B frag (8 bf16)
typedef float f32x4 __attribute__((ext_vector_type(4)));   // MFMA accumulator

#define SENT32 0x7F7F7F7Fu

__device__ __forceinline__ float b2f(u16 h) { return __uint_as_float(((u32)h) << 16); }
__device__ __forceinline__ u16 f2b(float x) {            // round-to-nearest-even
  u32 u = __float_as_uint(x);
  return (u16)((u + 0x7fffu + ((u >> 16) & 1u)) >> 16);
}
// A-side pair -> 3 u32 words: u16 stream {h0,l0,h0, h1,l1,h1}
__device__ __forceinline__ void packA3(float v0, float v1, u32& w0, u32& w1, u32& w2) {
  u16 h0 = f2b(v0), h1 = f2b(v1);
  u16 l0 = f2b(v0 - b2f(h0)), l1 = f2b(v1 - b2f(h1));
  w0 = (u32)h0 | ((u32)l0 << 16);
  w1 = (u32)h0 | ((u32)h1 << 16);
  w2 = (u32)l1 | ((u32)h1 << 16);
}
// B-side pair -> 3 u32 words: u16 stream {h0,h0,l0, h1,h1,l1}
__device__ __forceinline__ void packB3(float v0, float v1, u32& w0, u32& w1, u32& w2) {
  u16 h0 = f2b(v0), h1 = f2b(v1);
  u16 l0 = f2b(v0 - b2f(h0)), l1 = f2b(v1 - b2f(h1));
  w0 = (u32)h0 | ((u32)h0 << 16);
  w1 = (u32)l0 | ((u32)h1 << 16);
  w2 = (u32)h1 | ((u32)l1 << 16);
}

// ---------------------------------------------------------------- embed -> A3 triple
__global__ __launch_bounds__(256) void k_embed(const int* __restrict__ x,
    const float* __restrict__ lang, const float* __restrict__ emb, u16* __restrict__ A3) {
  const int m = blockIdx.x;                  // 8192 rows = b*512+s
  const int k = threadIdx.x * 4;             // 4 source elems
  const float* src = (k < 768) ? (lang + (size_t)m * 768 + k)
                               : (emb + (size_t)x[m] * 256 + (k - 768));
  float4 v = *(const float4*)src;
  u32 w0, w1, w2, w3, w4, w5;
  packA3(v.x, v.y, w0, w1, w2);
  packA3(v.z, v.w, w3, w4, w5);
  uint2* dst = (uint2*)(A3 + (size_t)m * 3072 + 3 * k);
  dst[0] = make_uint2(w0, w1); dst[1] = make_uint2(w2, w3); dst[2] = make_uint2(w4, w5);
}

// ---------------------------------------------------------------- weight preps
// fp32 W [rows][1024] -> triple [rows][3072]; one quad per thread.
__global__ __launch_bounds__(256) void k_prepw(const float* __restrict__ W,
    u16* __restrict__ W3, int nq) {
  const int idx = blockIdx.x * 256 + threadIdx.x;
  if (idx >= nq) return;
  const int base = idx * 4, row = base >> 10, k = base & 1023;
  float4 v = *(const float4*)(W + base);
  u32 w0, w1, w2, w3, w4, w5;
  packB3(v.x, v.y, w0, w1, w2);
  packB3(v.z, v.w, w3, w4, w5);
  uint2* dst = (uint2*)(W3 + (size_t)row * 3072 + 3 * k);
  dst[0] = make_uint2(w0, w1); dst[1] = make_uint2(w2, w3); dst[2] = make_uint2(w4, w5);
}
// Whh fp32 flat [4194304] -> hi bf16 plane (lo plane dropped in recurrence)
__global__ __launch_bounds__(256) void k_prepwh(const float* __restrict__ W,
    u16* __restrict__ hi) {
  const int idx = blockIdx.x * 256 + threadIdx.x;   // 1,048,576 quads
  const int base = idx * 4;
  float4 v = *(const float4*)(W + base);
  float vv[4] = {v.x, v.y, v.z, v.w};
  u16 h[4];
#pragma unroll
  for (int i = 0; i < 4; ++i) h[i] = f2b(vv[i]);
  *(uint2*)(hi + base) = make_uint2((u32)h[0] | ((u32)h[1] << 16), (u32)h[2] | ((u32)h[3] << 16));
}
__global__ __launch_bounds__(256) void k_prepb(const float* __restrict__ bih,
    const float* __restrict__ bhh, float* __restrict__ bsum) {
  const int tid = blockIdx.x * 256 + threadIdx.x;   // 8192
  bsum[tid] = bih[tid] + bhh[tid];
}
// act fp32 [8192][1024] -> A3 triple
__global__ __launch_bounds__(256) void k_tri(const float* __restrict__ act, u16* __restrict__ A3) {
  const int idx = blockIdx.x * 256 + threadIdx.x;   // 2,097,152 quads
  const int base = idx * 4, row = base >> 10, k = base & 1023;
  float4 v = *(const float4*)(act + base);
  u32 w0, w1, w2, w3, w4, w5;
  packA3(v.x, v.y, w0, w1, w2);
  packA3(v.z, v.w, w3, w4, w5);
  uint2* dst = (uint2*)(A3 + (size_t)row * 3072 + 3 * k);
  dst[0] = make_uint2(w0, w1); dst[1] = make_uint2(w2, w3); dst[2] = make_uint2(w4, w5);
}

// ---------------------------------------------------------------- GEMM (m97 style)
// C[m][n] = sum_k A[m][k]*B[n][k] + bias[n]. 128x128 tile, BK=32, 4 waves.
// EPI=0: fp32 -> xg layout [dir=n>>11][(s*16+b)][n&2047]  (N==4096)
// EPI=1: fp32 [m][N] + leaky-relu -> act.
template <int EPI>
__global__ __launch_bounds__(256) void k_gemm(const u16* __restrict__ A,
    const u16* __restrict__ B, const float* __restrict__ bias, float* __restrict__ outp,
    int Ka, int N) {
  __shared__ u16 As[4096];   // [128][32]
  __shared__ u16 Bs[4096];
  const int tid = threadIdx.x, wave = tid >> 6, lane = tid & 63;
  const int bm0 = blockIdx.x * 128, bn0 = blockIdx.y * 128;
  const int wm = (wave & 1) * 64, wn = (wave >> 1) * 64;
  const int kq = (lane >> 4) * 8;
  f32x4 acc[4][4];
#pragma unroll
  for (int i = 0; i < 4; ++i)
#pragma unroll
    for (int j = 0; j < 4; ++j) acc[i][j] = (f32x4){0.f, 0.f, 0.f, 0.f};

  const int srow = tid >> 2, soff = (tid & 3) * 8;
  const u16* Ag  = A + (size_t)(bm0 + srow) * Ka + soff;
  const u16* Ag2 = Ag + (size_t)64 * Ka;
  const u16* Bg  = B + (size_t)(bn0 + srow) * Ka + soff;
  const u16* Bg2 = Bg + (size_t)64 * Ka;
  u16* sA = As + wave * 512;
  u16* sB = Bs + wave * 512;

  for (int k0 = 0; k0 < Ka; k0 += 32) {
    __syncthreads();
    __builtin_amdgcn_global_load_lds((const __attribute__((address_space(1))) void*)(Ag + k0),
        (__attribute__((address_space(3))) void*)sA, 16, 0, 0);
    __builtin_amdgcn_global_load_lds((const __attribute__((address_space(1))) void*)(Ag2 + k0),
        (__attribute__((address_space(3))) void*)(sA + 2048), 16, 0, 0);
    __builtin_amdgcn_global_load_lds((const __attribute__((address_space(1))) void*)(Bg + k0),
        (__attribute__((address_space(3))) void*)sB, 16, 0, 0);
    __builtin_amdgcn_global_load_lds((const __attribute__((address_space(1))) void*)(Bg2 + k0),
        (__attribute__((address_space(3))) void*)(sB + 2048), 16, 0, 0);
    __syncthreads();
    s16x8 af[4], bf[4];
#pragma unroll
    for (int mi = 0; mi < 4; ++mi) af[mi] = *(const s16x8*)(As + (wm + mi * 16 + (lane & 15)) * 32 + kq);
#pragma unroll
    for (int ni = 0; ni < 4; ++ni) bf[ni] = *(const s16x8*)(Bs + (wn + ni * 16 + (lane & 15)) * 32 + kq);
#pragma unroll
    for (int mi = 0; mi < 4; ++mi)
#pragma unroll
      for (int ni = 0; ni < 4; ++ni)
        acc[mi][ni] = __builtin_amdgcn_mfma_f32_16x16x32_bf16(af[mi], bf[ni], acc[mi][ni], 0, 0, 0);
  }

#pragma unroll
  for (int mi = 0; mi < 4; ++mi)
#pragma unroll
    for (int r = 0; r < 4; ++r) {
      const int m = bm0 + wm + mi * 16 + (lane >> 4) * 4 + r;
#pragma unroll
      for (int ni = 0; ni < 4; ++ni) {
        const int n = bn0 + wn + ni * 16 + (lane & 15);
        float v = acc[mi][ni][r] + bias[n];
        if (EPI == 0) {
          const size_t off = (size_t)(n >> 11) * 16777216u
                           + (size_t)((m & 511) * 16 + (m >> 9)) * 2048 + (n & 2047);
          outp[off] = v;
        } else {
          v = (v > 0.f) ? v : 0.01f * v;
          outp[(size_t)m * N + n] = v;
        }
      }
    }
}

// ---------------------------------------------------------------- persistent biLSTM v5
// 32 WGs: dir = blk>>4; each WG owns 32 hidden units (4 gates x 16 batches).
// Wave g = gate g, 2 column-tiles of 16 units. W_hi frags pinned in VGPRs.
// Per-step slot g = dir*512 + step: {hi[16][512], lo[16][512]} bf16 planes
// (32KB). Producer: 2 relaxed AGENT u32 stores after pointwise (no barrier,
// no flag). Consumer: staging thread polls its 16 u64 until no u32 == SENT32,
// ds_write_b64 into padded hs rows (520 u16). 2 barriers/step.
__global__ __launch_bounds__(256, 1) void k_rec(const float* __restrict__ xg,
    const u16* __restrict__ WhiP, const int* __restrict__ lens, u16* __restrict__ Yt,
    u16* __restrict__ stepA, u16* __restrict__ stepB) {
  __shared__ u16 hs[2 * 16 * 520];     // [plane hi/lo][batch][512+8 pad]
  __shared__ float gx[4][16][33];      // [gate][batch][32 units + pad]
  const int tid = threadIdx.x, wave = tid >> 6, lane = tid & 63;
  const int dir = blockIdx.x >> 4, slice = blockIdx.x & 15, ubase = slice * 32;
  const int kq = (lane >> 4) * 8;
  const int col = lane & 15;
  const int bq = (lane >> 4) * 4;

  s16x8 bfrag[2][16];                  // W_hi rows g = wave*512 + ubase + j*16 + col
#pragma unroll
  for (int j = 0; j < 2; ++j) {
    const u16* wr = WhiP + ((size_t)dir * 2048 + wave * 512 + ubase + j * 16 + col) * 512 + kq;
#pragma unroll
    for (int kt = 0; kt < 16; ++kt) bfrag[j][kt] = *(const s16x8*)(wr + kt * 32);
  }
  const int pp = tid & 15, bb = tid >> 4;   // pointwise: units 2pp,2pp+1, batch bb
  const int len_b = lens[bb];
  float c0 = 0.f, h0v = 0.f, c1 = 0.f, h1v = 0.f;
  const float* xgp = xg + (size_t)dir * 16777216u;
  // staging thread coords: plane sp, batch row srow, 64B-interleaved chunk soff
  const int sp = tid >> 7, srow = (tid & 127) >> 3, soff = tid & 7;

  for (int s = 0; s < 512; ++s) {
    const int t = dir ? (511 - s) : s;
    // prefetch this step's xg (in flight during poll); acc rows b=bq+r, cols j*16+col
    const float* xr = xgp + ((size_t)t * 16 + bq) * 2048 + wave * 512 + ubase + col;
    f32x4 a0, a1;
    a0[0] = xr[0];  a0[1] = xr[2048]; a0[2] = xr[4096]; a0[3] = xr[6144];
    a1[0] = xr[16]; a1[1] = xr[2064]; a1[2] = xr[4112]; a1[3] = xr[6160];

    if (s > 0) {
      // read slot g = dir*512 + s : poll data directly (sentinel protocol)
      const int g = dir * 512 + s;
      const u64* slot64 = (const u64*)((g < 768) ? (stepA + (size_t)g * 16384)
                                                 : (stepB + (size_t)(g - 768) * 16384));
      const u64* src = slot64 + sp * 2048 + srow * 128 + soff;
      u64 wv[16];
      bool ok;
      do {
#pragma unroll
        for (int i = 0; i < 16; ++i)
          wv[i] = __hip_atomic_load(src + i * 8, __ATOMIC_RELAXED, __HIP_MEMORY_SCOPE_AGENT);
        ok = true;
#pragma unroll
        for (int i = 0; i < 16; ++i)
          ok &= ((u32)wv[i] != SENT32) & ((u32)(wv[i] >> 32) != SENT32);
      } while (!ok);
      u64* drow = (u64*)(hs + sp * 8320 + srow * 520);
#pragma unroll
      for (int i = 0; i < 16; ++i) drow[soff + i * 8] = wv[i];
    }
    __syncthreads();                     // B1: staging -> ds_read
    if (s > 0) {
      f32x4 l0 = (f32x4){0.f, 0.f, 0.f, 0.f}, l1 = (f32x4){0.f, 0.f, 0.f, 0.f};
      const u16* hh = hs + col * 520 + kq;     // A row = batch = col
      const u16* hl = hh + 8320;
#pragma unroll
      for (int kt = 0; kt < 16; ++kt) {
        s16x8 ah = *(const s16x8*)(hh + kt * 32);
        s16x8 al = *(const s16x8*)(hl + kt * 32);
        a0 = __builtin_amdgcn_mfma_f32_16x16x32_bf16(ah, bfrag[0][kt], a0, 0, 0, 0);
        a1 = __builtin_amdgcn_mfma_f32_16x16x32_bf16(ah, bfrag[1][kt], a1, 0, 0, 0);
        l0 = __builtin_amdgcn_mfma_f32_16x16x32_bf16(al, bfrag[0][kt], l0, 0, 0, 0);
        l1 = __builtin_amdgcn_mfma_f32_16x16x32_bf16(al, bfrag[1][kt], l1, 0, 0, 0);
      }
      a0 += l0; a1 += l1;
    }
#pragma unroll
    for (int r = 0; r < 4; ++r) {
      gx[wave][bq + r][col] = a0[r];
      gx[wave][bq + r][16 + col] = a1[r];
    }
    __syncthreads();                     // B2: gx write -> read

    const int u0 = 2 * pp, u1 = u0 + 1;
    const float gi0 = gx[0][bb][u0], gf0 = gx[1][bb][u0], gg0 = gx[2][bb][u0], go0 = gx[3][bb][u0];
    const float gi1 = gx[0][bb][u1], gf1 = gx[1][bb][u1], gg1 = gx[2][bb][u1], go1 = gx[3][bb][u1];
    const float ii0 = 1.f / (1.f + __expf(-gi0)),  ii1 = 1.f / (1.f + __expf(-gi1));
    const float ff0 = 1.f / (1.f + __expf(-gf0)),  ff1 = 1.f / (1.f + __expf(-gf1));
    const float gz0 = 1.f - 2.f / (__expf(2.f * gg0) + 1.f);   // tanh
    const float gz1 = 1.f - 2.f / (__expf(2.f * gg1) + 1.f);
    const float oo0 = 1.f / (1.f + __expf(-go0)),  oo1 = 1.f / (1.f + __expf(-go1));
    const float cn0 = ff0 * c0 + ii0 * gz0,        cn1 = ff1 * c1 + ii1 * gz1;
    const float hn0 = oo0 * (1.f - 2.f / (__expf(2.f * cn0) + 1.f));
    const float hn1 = oo1 * (1.f - 2.f / (__expf(2.f * cn1) + 1.f));
    const bool mk = (t < len_b);
    c0 = mk ? cn0 : c0;  h0v = mk ? hn0 : h0v;
    c1 = mk ? cn1 : c1;  h1v = mk ? hn1 : h1v;
    const float y0 = mk ? hn0 : 0.f, y1 = mk ? hn1 : 0.f;

    if (s < 511) {                       // publish carried h pair to slot g+1
      const u16 s0h = f2b(h0v), s0l = f2b(h0v - b2f(s0h));
      const u16 s1h = f2b(h1v), s1l = f2b(h1v - b2f(s1h));
      const int gw = dir * 512 + s + 1;
      u16* slot = (gw < 768) ? (stepA + (size_t)gw * 16384)
                             : (stepB + (size_t)(gw - 768) * 16384);
      u32* dh = (u32*)(slot + (size_t)bb * 512 + ubase) + pp;          // hi plane
      u32* dl = (u32*)(slot + 8192 + (size_t)bb * 512 + ubase) + pp;   // lo plane
      __hip_atomic_store(dh, (u32)s0h | ((u32)s1h << 16), __ATOMIC_RELAXED, __HIP_MEMORY_SCOPE_AGENT);
      __hip_atomic_store(dl, (u32)s0l | ((u32)s1l << 16), __ATOMIC_RELAXED, __HIP_MEMORY_SCOPE_AGENT);
    }

    // output: next-layer A-triple {hi,lo,hi} of y = h_new*mask (unit pair -> 12B);
    // no ordering needed (consumed by later kernel; kernel end drains).
    u32 w0, w1, w2;
    packA3(y0, y1, w0, w1, w2);
    const int ug = dir * 512 + ubase + u0;               // even
    u32* yp = (u32*)(Yt + (size_t)(bb * 512 + t) * 3072 + 3 * ug);
    yp[0] = w0; yp[1] = w1; yp[2] = w2;
  }
}

// ---------------------------------------------------------------- head: out = a2 @ W3^T + b3
__global__ __launch_bounds__(256) void k_head(const float* __restrict__ a2,
    const float* __restrict__ W3, const float* __restrict__ b3, float* __restrict__ out) {
  const int m = (blockIdx.x * 256 + threadIdx.x) >> 6;   // wave per row
  const int lane = threadIdx.x & 63;
  const float* row = a2 + (size_t)m * 1024;
  float s[5] = {0.f, 0.f, 0.f, 0.f, 0.f};
  for (int j = lane; j < 1024; j += 64) {
    const float v = row[j];
#pragma unroll
    for (int c = 0; c < 5; ++c) s[c] += v * W3[c * 1024 + j];
  }
#pragma unroll
  for (int c = 0; c < 5; ++c)
    for (int off = 32; off > 0; off >>= 1) s[c] += __shfl_down(s[c], off, 64);
  if (lane == 0)
#pragma unroll
    for (int c = 0; c < 5; ++c) out[(size_t)m * 5 + c] = s[c] + b3[c];   // fp32 output
}

// ---------------------------------------------------------------- launch
extern "C" void kernel_launch(void* const* d_in, const int* in_sizes, int n_in,
                              void* d_out, int out_size, void* d_ws, size_t ws_size,
                              hipStream_t stream) {
  const int*   x    = (const int*)d_in[0];
  const int*   lens = (const int*)d_in[1];
  const float* lang = (const float*)d_in[2];
  const float* emb  = (const float*)d_in[3];
  const float* Wih  = (const float*)d_in[4];   // [2][2][2048][1024]
  const float* Whh  = (const float*)d_in[5];   // [2][2][2048][512]
  const float* bih  = (const float*)d_in[6];
  const float* bhh  = (const float*)d_in[7];
  const float* W1   = (const float*)d_in[8];
  const float* b1   = (const float*)d_in[9];
  const float* W2   = (const float*)d_in[10];
  const float* b2   = (const float*)d_in[11];
  const float* W3   = (const float*)d_in[12];
  const float* b3   = (const float*)d_in[13];
  float* out = (float*)d_out;
  char* ws = (char*)d_ws;

  // workspace (~223 MiB). act overlays xg (xg dead after k_rec layer 1).
  // stepA overlays wb3 (wb3 dead during k_rec); stepB is the 8.39MB hole.
  float* xg     = (float*)(ws + 0);             // [2][8192][2048] f32  134,217,728
  float* act    = (float*)(ws + 0);             //  [8192][1024] f32 overlay
  u16*   A3     = (u16*)(ws + 134217728);       //  [8192][3072] u16     50,331,648
  u16*   wb3    = (u16*)(ws + 184549376);       //  [4096][3072] u16     25,165,824
  u16*   stepA  = (u16*)(ws + 184549376);       //  768 slots x 32KB overlay of wb3
  u16*   whh_hi = (u16*)(ws + 209715200);       //  [2][2][2048][512]     8,388,608
  u16*   stepB  = (u16*)(ws + 218103808);       //  256 slots x 32KB      8,388,608
  u16*   w3b    = (u16*)(ws + 226492416);       //  [1024][3072] u16      6,291,456
  float* bsum   = (float*)(ws + 233046016);     //  [2][2][2048]             32,768

  k_prepb<<<32, 256, 0, stream>>>(bih, bhh, bsum);
  k_prepwh<<<4096, 256, 0, stream>>>(Whh, whh_hi);
  k_embed<<<8192, 256, 0, stream>>>(x, lang, emb, A3);

  // layer 0
  k_prepw<<<4096, 256, 0, stream>>>(Wih, wb3, 1048576);
  k_gemm<0><<<dim3(64, 32), 256, 0, stream>>>(A3, wb3, bsum, xg, 3072, 4096);
  hipMemsetAsync(stepA, 0x7F, 25165824, stream);   // sentinel-fill (wb3 dead now)
  hipMemsetAsync(stepB, 0x7F, 8388608, stream);
  k_rec<<<32, 256, 0, stream>>>(xg, whh_hi, lens, A3, stepA, stepB);
  // layer 1
  k_prepw<<<4096, 256, 0, stream>>>(Wih + 4194304, wb3, 1048576);
  k_gemm<0><<<dim3(64, 32), 256, 0, stream>>>(A3, wb3, bsum + 4096, xg, 3072, 4096);
  hipMemsetAsync(stepA, 0x7F, 25165824, stream);
  hipMemsetAsync(stepB, 0x7F, 8388608, stream);
  k_rec<<<32, 256, 0, stream>>>(xg, whh_hi + 2097152, lens, A3, stepA, stepB);
  // head
  k_prepw<<<1024, 256, 0, stream>>>(W1, w3b, 262144);
  k_gemm<1><<<dim3(64, 8), 256, 0, stream>>>(A3, w3b, b1, act, 3072, 1024);
  k_tri<<<8192, 256, 0, stream>>>(act, A3);
  k_prepw<<<1024, 256, 0, stream>>>(W2, w3b, 262144);
  k_gemm<1><<<dim3(64, 8), 256, 0, stream>>>(A3, w3b, b2, act, 3072, 1024);
  k_head<<<2048, 256, 0, stream>>>(act, W3, b3, out);
}